// Round 7
// baseline (1649.025 us; speedup 1.0000x reference)
//
#include <hip/hip_runtime.h>
#include <math.h>

#define SQ 1024  // S
#define EE 512   // E
#define NB 4     // B
#define NH 8     // H

// Optimization barrier: forces materialization (rounding) so the compiler
// cannot FMA-contract or reassociate across numpy's op boundaries.
__device__ __forceinline__ float sep(float x) {
  asm volatile("" : "+v"(x));
  return x;
}

// ================= LayerNorm, numpy-exact fp32 (np.mean pairwise) =================
__global__ __launch_bounds__(64) void ln_np(const float* __restrict__ x,
                                            const float* __restrict__ g,
                                            const float* __restrict__ b,
                                            float* __restrict__ y) {
  __shared__ float xs[EE];
  __shared__ float bc[2];
  long long t = blockIdx.x;
  int lane = threadIdx.x;
#pragma unroll
  for (int m = 0; m < 8; m++) xs[lane + 64 * m] = x[t * EE + lane + 64 * m];
  __syncthreads();
  int l = lane >> 3, a = lane & 7;
  // ---- mean: pairwise_sum(512) = (L0+L1)+(L2+L3), leaf=128 w/ 8 accumulators
  float r = 0.f;
  if (lane < 32) {
    r = xs[l * 128 + a];
#pragma unroll
    for (int m = 1; m < 16; m++) r = r + xs[l * 128 + 8 * m + a];
  }
  r = r + __shfl_xor(r, 1);
  r = r + __shfl_xor(r, 2);
  r = r + __shfl_xor(r, 4);
  r = r + __shfl_xor(r, 8);
  r = r + __shfl_xor(r, 16);
  if (lane == 0) bc[0] = r / 512.0f;
  __syncthreads();
  float mean = bc[0];
  // ---- var ----
  r = 0.f;
  if (lane < 32) {
#pragma unroll
    for (int m = 0; m < 16; m++) {
      float d = sep(xs[l * 128 + 8 * m + a] - mean);
      float s2 = sep(d * d);
      r = (m == 0) ? s2 : (r + s2);
    }
  }
  r = r + __shfl_xor(r, 1);
  r = r + __shfl_xor(r, 2);
  r = r + __shfl_xor(r, 4);
  r = r + __shfl_xor(r, 8);
  r = r + __shfl_xor(r, 16);
  if (lane == 0) bc[1] = r / 512.0f;
  __syncthreads();
  float var = bc[1];
  float rs = 1.0f / sqrtf(var + 1e-5f);
#pragma unroll
  for (int m = 0; m < 8; m++) {
    int i = lane + 64 * m;
    float d = sep(xs[i] - mean);
    float t1 = sep(d * rs);
    float t2 = sep(t1 * g[i]);
    y[t * EE + i] = t2 + b[i];
  }
}

// ================= distances =================
// d = ((conv_b + E0) + E1) + E2, each E_k an ascending-e FMA chain (BLAS/
// contracted-scalar order), each combining add rounded. tanh via fp64 (≈CR).
__global__ __launch_bounds__(256) void dist_np(const float* __restrict__ nq,
                                               const float* __restrict__ conv_w,
                                               const float* __restrict__ conv_b,
                                               float* __restrict__ dist) {
  int bh = blockIdx.x;
  int b = bh >> 3, h = bh & 7;
  float cb = conv_b[h];
  const float* W = conv_w + (long long)h * EE * 3;
  for (int s = threadIdx.x; s < SQ; s += 256) {
    float d = cb;
#pragma unroll
    for (int k = 0; k < 3; k++) {
      int t = s - 2 + k;
      if (t < 0) continue;  // padded rows contribute exactly 0
      const float* row = nq + ((long long)b * SQ + t) * EE;
      float acc = 0.f;
      for (int e = 0; e < EE; e++) acc = __builtin_fmaf(row[e], W[e * 3 + k], acc);
      d = sep(d + acc);
    }
    dist[(long long)bh * SQ + s] = (float)tanh((double)d);
  }
}

// ================= fp32 tiled NT-GEMM =================
// Emulates OpenBLAS sgemm rounding: per output element, ascending-k FMA chain
// into a single accumulator; SPLITK>0 models the KC blocking (Haswell/Zen
// KC=384): separate accumulator for k>=SPLITK, one rounded `C +=` merge.
// ACT: 0 = acc*alpha+bias(+Res), 1 = gelu(acc+bias), 2 = acc / alpha (numpy
// divides scores by fl32(sqrt(E))).
__device__ __forceinline__ float gelu_exact(float x) {
  return 0.5f * x * (1.f + erff(x / 1.41421356237309504880f));
}

template <int ACT, int SPLITK>
__global__ __launch_bounds__(256) void gemm_nt(const float* __restrict__ A, int lda, long long sA,
                                               const float* __restrict__ B, int ldb, long long sB,
                                               const float* __restrict__ bias,
                                               const float* __restrict__ Res,
                                               float* __restrict__ C, int ldc, long long sC,
                                               int K, float alpha) {
  __shared__ float As[16][68];
  __shared__ float Bs[16][68];
  int z = blockIdx.z;
  A += (long long)z * sA;
  B += (long long)z * sB;
  C += (long long)z * sC;
  int m0 = blockIdx.y * 64, n0 = blockIdx.x * 64;
  int tid = threadIdx.x;
  int lr = tid >> 2, lc = tid & 3;
  int tx = tid & 15, ty = tid >> 4;
  float acc[4][4] = {};
  float acc2[4][4] = {};
  const float* Arow = A + (long long)(m0 + lr) * lda + lc * 4;
  const float* Brow = B + (long long)(n0 + lr) * ldb + lc * 4;
  for (int k0 = 0; k0 < K; k0 += 16) {
    float4 a4 = *(const float4*)(Arow + k0);
    float4 b4 = *(const float4*)(Brow + k0);
    __syncthreads();
    As[lc * 4 + 0][lr] = a4.x; As[lc * 4 + 1][lr] = a4.y;
    As[lc * 4 + 2][lr] = a4.z; As[lc * 4 + 3][lr] = a4.w;
    Bs[lc * 4 + 0][lr] = b4.x; Bs[lc * 4 + 1][lr] = b4.y;
    Bs[lc * 4 + 2][lr] = b4.z; Bs[lc * 4 + 3][lr] = b4.w;
    __syncthreads();
    float(*tgt)[4] = (SPLITK > 0 && k0 >= SPLITK) ? acc2 : acc;
#pragma unroll
    for (int kk = 0; kk < 16; kk++) {
      float4 av = *(const float4*)&As[kk][ty * 4];
      float4 bv = *(const float4*)&Bs[kk][tx * 4];
      float a[4] = {av.x, av.y, av.z, av.w};
      float bb[4] = {bv.x, bv.y, bv.z, bv.w};
#pragma unroll
      for (int i = 0; i < 4; i++)
#pragma unroll
        for (int j = 0; j < 4; j++) tgt[i][j] += a[i] * bb[j];
    }
  }
  if (SPLITK > 0) {
#pragma unroll
    for (int i = 0; i < 4; i++)
#pragma unroll
      for (int j = 0; j < 4; j++) acc[i][j] = sep(acc[i][j]) + acc2[i][j];
  }
  float4 bias4 = make_float4(0.f, 0.f, 0.f, 0.f);
  if (ACT != 2 && bias) bias4 = *(const float4*)(bias + n0 + tx * 4);
#pragma unroll
  for (int i = 0; i < 4; i++) {
    int row = m0 + ty * 4 + i;
    float o[4];
    if (ACT == 2) {
#pragma unroll
      for (int j = 0; j < 4; j++) o[j] = acc[i][j] / alpha;  // true division
    } else {
      o[0] = sep(acc[i][0] * alpha) + bias4.x;
      o[1] = sep(acc[i][1] * alpha) + bias4.y;
      o[2] = sep(acc[i][2] * alpha) + bias4.z;
      o[3] = sep(acc[i][3] * alpha) + bias4.w;
    }
    if (ACT == 1) {
#pragma unroll
      for (int j = 0; j < 4; j++) o[j] = gelu_exact(o[j]);
    }
    if (Res) {
      float4 r4 = *(const float4*)(Res + (long long)row * ldc + n0 + tx * 4);
      o[0] = sep(o[0]) + r4.x; o[1] = sep(o[1]) + r4.y;
      o[2] = sep(o[2]) + r4.z; o[3] = sep(o[3]) + r4.w;
    }
    *(float4*)(C + (long long)row * ldc + n0 + tx * 4) = make_float4(o[0], o[1], o[2], o[3]);
  }
}

// ================= gated row sums: np.sum pairwise(1024) exact =================
__global__ __launch_bounds__(64) void rowsum_np(const float* __restrict__ scores,
                                                const float* __restrict__ dist,
                                                float* __restrict__ invrs) {
  __shared__ float wsm[SQ];
  int i = blockIdx.x;
  int z = blockIdx.y;
  int b = z >> 3;
  const float* srow = scores + ((long long)b * SQ + i) * SQ;
  const float* dz = dist + (long long)z * SQ;
  float di = dz[i];
  int lane = threadIdx.x;
#pragma unroll
  for (int m = 0; m < 16; m++) {
    int j = lane + 64 * m;
    float e = (float)exp((double)(dz[j] - di));  // ≈ correctly-rounded expf
    float gg = 1.f / (1.f + e);
    wsm[j] = srow[j] * gg;  // materialized fl(s*g)
  }
  __syncthreads();
  int l = lane >> 3, a = lane & 7;
  float r = wsm[l * 128 + a];
#pragma unroll
  for (int m = 1; m < 16; m++) r = r + wsm[l * 128 + 8 * m + a];
  r = r + __shfl_xor(r, 1);
  r = r + __shfl_xor(r, 2);
  r = r + __shfl_xor(r, 4);
  r = r + __shfl_xor(r, 8);
  r = r + __shfl_xor(r, 16);
  r = r + __shfl_xor(r, 32);
  if (lane == 0) invrs[(long long)z * SQ + i] = 1.f / (r + 1e-12f);
}

// ================= ctx GEMM (numerator; relative error only) =================
__global__ __launch_bounds__(256) void ctx_gemm(const float* __restrict__ scores,
                                                const float* __restrict__ dist,
                                                const float* __restrict__ invrs,
                                                const float* __restrict__ qkv,
                                                float* __restrict__ ctx) {
  __shared__ float As[16][68];
  __shared__ float Bs[16][68];
  int z = blockIdx.z, b = z >> 3, h = z & 7;
  const float* A = scores + (long long)b * SQ * SQ;
  const float* V = qkv + (long long)b * SQ * (3 * EE) + 2 * EE;
  float* C = ctx + (long long)b * SQ * (NH * EE) + h * EE;
  const float* dz = dist + (long long)z * SQ;
  int m0 = blockIdx.y * 64, n0 = blockIdx.x * 64;
  int tid = threadIdx.x;
  int lr = tid >> 2, lc = tid & 3;
  int bk = tid >> 4, bc = tid & 15;
  int tx = tid & 15, ty = tid >> 4;
  int arow = m0 + lr;
  float di = dz[arow];
  float inv = invrs[(long long)z * SQ + arow];
  float acc[4][4] = {};
  for (int k0 = 0; k0 < SQ; k0 += 16) {
    float4 s4 = *(const float4*)(A + (long long)arow * SQ + k0 + lc * 4);
    float g0 = 1.f / (1.f + expf(dz[k0 + lc * 4 + 0] - di));
    float g1 = 1.f / (1.f + expf(dz[k0 + lc * 4 + 1] - di));
    float g2 = 1.f / (1.f + expf(dz[k0 + lc * 4 + 2] - di));
    float g3 = 1.f / (1.f + expf(dz[k0 + lc * 4 + 3] - di));
    float4 v4 = *(const float4*)(V + (long long)(k0 + bk) * (3 * EE) + n0 + bc * 4);
    __syncthreads();
    As[lc * 4 + 0][lr] = (s4.x * g0) * inv;
    As[lc * 4 + 1][lr] = (s4.y * g1) * inv;
    As[lc * 4 + 2][lr] = (s4.z * g2) * inv;
    As[lc * 4 + 3][lr] = (s4.w * g3) * inv;
    *(float4*)&Bs[bk][bc * 4] = v4;
    __syncthreads();
#pragma unroll
    for (int kk = 0; kk < 16; kk++) {
      float4 av = *(const float4*)&As[kk][ty * 4];
      float4 bv = *(const float4*)&Bs[kk][tx * 4];
      float a[4] = {av.x, av.y, av.z, av.w};
      float bb[4] = {bv.x, bv.y, bv.z, bv.w};
#pragma unroll
      for (int i = 0; i < 4; i++)
#pragma unroll
        for (int j = 0; j < 4; j++) acc[i][j] += a[i] * bb[j];
    }
  }
#pragma unroll
  for (int i = 0; i < 4; i++) {
    int row = m0 + ty * 4 + i;
    *(float4*)(C + (long long)row * (NH * EE) + n0 + tx * 4) =
        make_float4(acc[i][0], acc[i][1], acc[i][2], acc[i][3]);
  }
}

extern "C" void kernel_launch(void* const* d_in, const int* in_sizes, int n_in,
                              void* d_out, int out_size, void* d_ws, size_t ws_size,
                              hipStream_t stream) {
  const float* query     = (const float*)d_in[0];
  const float* ln1_g     = (const float*)d_in[1];
  const float* ln1_b     = (const float*)d_in[2];
  const float* in_proj_w = (const float*)d_in[3];
  const float* in_proj_b = (const float*)d_in[4];
  const float* out_w     = (const float*)d_in[5];
  const float* out_b     = (const float*)d_in[6];
  const float* conv_w    = (const float*)d_in[7];
  const float* conv_b    = (const float*)d_in[8];
  const float* ln2_g     = (const float*)d_in[9];
  const float* ln2_b     = (const float*)d_in[10];
  const float* mlp_w1    = (const float*)d_in[11];
  const float* mlp_b1    = (const float*)d_in[12];
  const float* mlp_w2    = (const float*)d_in[13];
  const float* mlp_b2    = (const float*)d_in[14];
  float* out = (float*)d_out;
  char* ws = (char*)d_ws;

  float* nq     = (float*)(ws + 0);                      // 8 MiB
  float* qkv    = (float*)(ws + (8ull << 20));           // 24 MiB
  float* dist   = (float*)(ws + (32ull << 20));          // 128 KiB
  float* invrs  = (float*)(ws + (32ull << 20) + 131072); // 128 KiB
  float* scores = (float*)(ws + (32ull << 20) + 262144); // 16 MiB
  float* ctx    = (float*)(ws + (48ull << 20) + 262144); // 64 MiB -> 112.25 MiB
  float* ln2out = scores;                                // reuse
  float* hbuf   = nq;                                    // reuse nq+qkv (32 MiB)

  // 1. LN1 (numpy-pairwise fp32)
  ln_np<<<dim3(NB * SQ), 64, 0, stream>>>(query, ln1_g, ln1_b, nq);
  // 2. distances (ascending-e FMA per k, separate E_k adds)
  dist_np<<<dim3(NB * NH), 256, 0, stream>>>(nq, conv_w, conv_b, dist);
  // 3. qkv = nq @ in_proj_w^T + b  (sgemm KC=384 emulation)
  gemm_nt<0, 384><<<dim3(24, 64, 1), 256, 0, stream>>>(nq, EE, 0, in_proj_w, EE, 0,
                                                       in_proj_b, nullptr, qkv, 3 * EE, 0, EE, 1.f);
  // 4. scores = (q @ k^T) / fl32(sqrt(512))  — sgemm KC=384 + true division
  gemm_nt<2, 384><<<dim3(16, 16, NB), 256, 0, stream>>>(
      qkv, 3 * EE, (long long)SQ * 3 * EE, qkv + EE, 3 * EE, (long long)SQ * 3 * EE,
      nullptr, nullptr, scores, SQ, (long long)SQ * SQ, EE, sqrtf(512.0f));
  // 5. numpy-pairwise gated row sums -> reciprocals
  rowsum_np<<<dim3(SQ, NB * NH), 64, 0, stream>>>(scores, dist, invrs);
  // 6. ctx (batched over b,h)
  ctx_gemm<<<dim3(8, 16, NB * NH), 256, 0, stream>>>(scores, dist, invrs, qkv, ctx);
  // 7. attn_out = ctx @ out_w^T + out_b + query
  gemm_nt<0, 0><<<dim3(8, 64, 1), 256, 0, stream>>>(ctx, NH * EE, 0, out_w, NH * EE, 0,
                                                    out_b, query, out, EE, 0, NH * EE, 1.f);
  // 8. LN2
  ln_np<<<dim3(NB * SQ), 64, 0, stream>>>(out, ln2_g, ln2_b, ln2out);
  // 9. MLP1 + gelu
  gemm_nt<1, 0><<<dim3(32, 64, 1), 256, 0, stream>>>(ln2out, EE, 0, mlp_w1, EE, 0,
                                                     mlp_b1, nullptr, hbuf, 4 * EE, 0, EE, 1.f);
  // 10. MLP2 + residual
  gemm_nt<0, 0><<<dim3(8, 64, 1), 256, 0, stream>>>(hbuf, 4 * EE, 0, mlp_w2, 4 * EE, 0,
                                                    mlp_b2, out, out, EE, 0, 4 * EE, 1.f);
}